// Round 9
// baseline (819.618 us; speedup 1.0000x reference)
//
#include <hip/hip_runtime.h>
#include <stdint.h>

// Chamfer distance, B=4, N=M=8192, fp32 [B][N][3], out[B] = d01+d10.
//
// R9: R8's spill-storm post-mortem (944MB FETCH + 1.9GB WRITE of scratch
// traffic = 800us; explicit bv/nv rotation forced 4 live D-tiles + rotation
// regs past the 128-VGPR cap). Fix: keep the two structural wins, drop the
// hand pipeline:
//  - prep stays FUSED (raw points loaded issue-early per pass, fragments
//    built in-register, ds_written to the other buffer) -> no prep kernel,
//    no efrag roundtrip;
//  - inner loop reverted to R7's non-spilling form (4 MFMAs, two fmaxf
//    merge loops, compiler-scheduled LDS reads, setprio kept);
//  - tail collapsed: final = 4 blocks, both directions per block, plain
//    store -> no out-memset dispatch, no atomics. 5 dispatches -> 2.
// Numerics identical to the verified R2..R8 path (bf16-split K=14 dot,
// d' = q.p - 0.5|p|^2, chunk maxima -> exact fp32 reconstruction).

typedef __bf16 bf16x8 __attribute__((ext_vector_type(8)));
typedef float  f32x16 __attribute__((ext_vector_type(16)));
typedef float  f32x4  __attribute__((ext_vector_type(4)));

constexpr int B     = 4;
constexpr int NPTS  = 8192;
constexpr int BLOCK = 256;
constexpr int QPB   = 256;             // 4 waves * 64 queries
constexpr int QBLKS = NPTS / QPB;      // 32
constexpr int CH    = 4;               // point chunks per (b,dir)
constexpr int CPTS  = NPTS / CH;       // 2048 points per chunk
constexpr int SPTS  = 512;             // points per LDS pass (16 KB/buffer)
constexpr int NPASS = CPTS / SPTS;     // 4
constexpr int TPP   = SPTS / 32;       // 16 tiles per pass
constexpr int RSTRIDE = 36;            // padded f32 per reduce row
constexpr int SMEMB = BLOCK * RSTRIDE * 4;            // 36864 B (>2x16KB)

// ---- fragment builders (same bytes as the verified prep kernel) -----------
// e0(k0-7) = [pxh,pyh,pzh, pxl,pyl,pzl, pxh,pyh]
// e1(k8-15)= [pzh, nh, nl, pxl,pyl,pzl, 0, 0]
__device__ inline bf16x8 mk_e0(float x, float y, float z) {
    __bf16 hx = (__bf16)x, hy = (__bf16)y, hz = (__bf16)z;
    __bf16 lx = (__bf16)(x - (float)hx);
    __bf16 ly = (__bf16)(y - (float)hy);
    __bf16 lz = (__bf16)(z - (float)hz);
    return (bf16x8){hx, hy, hz, lx, ly, lz, hx, hy};
}
__device__ inline bf16x8 mk_e1(float x, float y, float z) {
    __bf16 hx = (__bf16)x, hy = (__bf16)y, hz = (__bf16)z;
    __bf16 lx = (__bf16)(x - (float)hx);
    __bf16 ly = (__bf16)(y - (float)hy);
    __bf16 lz = (__bf16)(z - (float)hz);
    float n = -0.5f * (x * x + y * y + z * z);
    __bf16 nh = (__bf16)n;
    __bf16 nl = (__bf16)(n - (float)nh);
    const __bf16 zb = (__bf16)0.0f;
    return (bf16x8){hz, nh, nl, lx, ly, lz, zb, zb};
}

// ---- Kernel 1: MFMA sweep (prep fused) ------------------------------------
__global__ __launch_bounds__(BLOCK, 4) void chamfer_sweep(
    const float* __restrict__ tpl, const float* __restrict__ src,
    float* __restrict__ cm)                  // [2*B][CH][NPTS] chunk maxima
{
    __shared__ char smem[SMEMB];             // 2x16KB dbuf / 36.9KB reduce

    const int tid = threadIdx.x;
    const int l   = tid & 63;
    const int w   = tid >> 6;
    const int h   = l >> 5;                  // k-group (0: k0-7, 1: k8-15)
    const int r32 = l & 31;                  // A row / B col within tile
    const int c   = blockIdx.z;              // dir*B + b
    const int b   = c & (B - 1);
    const int dir = c >> 2;
    const float* q  = (dir == 0 ? tpl : src) + (size_t)b * NPTS * 3;
    const float* db = (dir == 0 ? src : tpl) + (size_t)b * NPTS * 3;
    const int qbase = blockIdx.x * QPB + w * 64;
    const float2* g2 = (const float2*)(db + (size_t)blockIdx.y * CPTS * 3);

    // Issue pass-0 raw loads first; latency hides under the fa build.
    float2 ra = g2[3 * tid], rb = g2[3 * tid + 1], rc = g2[3 * tid + 2];

    // A fragments: row = r32, k = h*8 + e. 64 queries per wave.
    // g0 = [qxh,qyh,qzh, qxh,qyh,qzh, qxl,qyl]; g1 = [qzl,1,1, qxl,qyl,qzl,0,0]
    const __bf16 one = (__bf16)1.0f, zb = (__bf16)0.0f;
    bf16x8 fa[2];
    #pragma unroll
    for (int f = 0; f < 2; ++f) {
        int qi = qbase + f * 32 + r32;
        float x = q[3 * qi], y = q[3 * qi + 1], z = q[3 * qi + 2];
        __bf16 hx = (__bf16)x, hy = (__bf16)y, hz = (__bf16)z;
        __bf16 lx = (__bf16)(x - (float)hx);
        __bf16 ly = (__bf16)(y - (float)hy);
        __bf16 lz = (__bf16)(z - (float)hz);
        if (h == 0) fa[f] = (bf16x8){hx, hy, hz, hx, hy, hz, lx, ly};
        else        fa[f] = (bf16x8){lz, one, one, lx, ly, lz, zb, zb};
    }

    // Build + write pass-0 fragments into buffer 0.
    {
        float4* s4 = (float4*)smem;
        const int base0 = (tid >> 4) * 64 + ((2 * tid) & 31);
        bf16x8 e00 = mk_e0(ra.x, ra.y, rb.x), e10 = mk_e1(ra.x, ra.y, rb.x);
        bf16x8 e01 = mk_e0(rb.y, rc.x, rc.y), e11 = mk_e1(rb.y, rc.x, rc.y);
        s4[base0]      = *(float4*)&e00;
        s4[base0 + 1]  = *(float4*)&e01;
        s4[base0 + 32] = *(float4*)&e10;
        s4[base0 + 33] = *(float4*)&e11;
    }

    f32x16 best0, best1, zc;
    #pragma unroll
    for (int r = 0; r < 16; ++r) { best0[r] = -3.4e38f; best1[r] = -3.4e38f; zc[r] = 0.0f; }

    const int idx0 = h * 32 + r32;           // B-frag index within a tile
    for (int gp = 0; gp < NPASS; ++gp) {
        __syncthreads();                     // buf[gp&1] fully written
        if (gp + 1 < NPASS) {                // issue-early next raw loads
            int fi = 768 * (gp + 1) + 3 * tid;
            ra = g2[fi]; rb = g2[fi + 1]; rc = g2[fi + 2];
        }
        const bf16x8* sb = (const bf16x8*)(smem + (gp & 1) * 16384);
        __builtin_amdgcn_s_setprio(1);
        #pragma unroll
        for (int t = 0; t < TPP; t += 2) {
            bf16x8 bv0 = sb[t * 64 + idx0];
            bf16x8 bv1 = sb[(t + 1) * 64 + idx0];
            f32x16 d0 = __builtin_amdgcn_mfma_f32_32x32x16_bf16(fa[0], bv0, zc, 0, 0, 0);
            f32x16 d1 = __builtin_amdgcn_mfma_f32_32x32x16_bf16(fa[0], bv1, zc, 0, 0, 0);
            f32x16 e0 = __builtin_amdgcn_mfma_f32_32x32x16_bf16(fa[1], bv0, zc, 0, 0, 0);
            f32x16 e1 = __builtin_amdgcn_mfma_f32_32x32x16_bf16(fa[1], bv1, zc, 0, 0, 0);
            #pragma unroll
            for (int r = 0; r < 16; ++r)
                best0[r] = fmaxf(fmaxf(best0[r], d0[r]), d1[r]);   // -> v_max3
            #pragma unroll
            for (int r = 0; r < 16; ++r)
                best1[r] = fmaxf(fmaxf(best1[r], e0[r]), e1[r]);
        }
        __builtin_amdgcn_s_setprio(0);
        if (gp + 1 < NPASS) {                // build+write next pass's frags
            float4* s4 = (float4*)(smem + ((gp + 1) & 1) * 16384);
            const int base0 = (tid >> 4) * 64 + ((2 * tid) & 31);
            bf16x8 e00 = mk_e0(ra.x, ra.y, rb.x), e10 = mk_e1(ra.x, ra.y, rb.x);
            bf16x8 e01 = mk_e0(rb.y, rc.x, rc.y), e11 = mk_e1(rb.y, rc.x, rc.y);
            s4[base0]      = *(float4*)&e00;
            s4[base0 + 1]  = *(float4*)&e01;
            s4[base0 + 32] = *(float4*)&e10;
            s4[base0 + 33] = *(float4*)&e11;
        }
    }

    // Epilogue: LDS transpose reduce (no wave shuffles, no atomics).
    // D layout: col = r32, row = (r&3) + 8*(r>>2) + 4*h.
    __syncthreads();                         // all waves done reading sbuf
    float* red = (float*)smem;
    #pragma unroll
    for (int r = 0; r < 16; ++r) {
        int row = (r & 3) + 8 * (r >> 2) + 4 * h;
        red[(w * 64 + row) * RSTRIDE + r32]      = best0[r];
        red[(w * 64 + 32 + row) * RSTRIDE + r32] = best1[r];
    }
    __syncthreads();
    const float* rr = red + tid * RSTRIDE;   // 144B stride: 2-way only (free)
    float m = -3.4e38f;
    #pragma unroll
    for (int j = 0; j < 8; ++j) {
        f32x4 v = *(const f32x4*)(rr + 4 * j);
        m = fmaxf(m, fmaxf(fmaxf(v.x, v.y), fmaxf(v.z, v.w)));
    }
    cm[((size_t)c * CH + blockIdx.y) * NPTS + blockIdx.x * QPB + tid] = m;
}

// ---- Kernel 2: out[b] = mean_q dist0 + mean_q dist1 (plain store) ---------
__global__ __launch_bounds__(256) void chamfer_final(
    const float* __restrict__ tpl, const float* __restrict__ src,
    const float* __restrict__ cm, float* __restrict__ out)
{
    __shared__ float red[256];
    const int b = blockIdx.x;
    const float* q0 = tpl + (size_t)b * NPTS * 3;      // dir0 queries
    const float* q1 = src + (size_t)b * NPTS * 3;      // dir1 queries
    const float* c0 = cm + (size_t)b * CH * NPTS;
    const float* c1 = cm + (size_t)(B + b) * CH * NPTS;

    float s = 0.f;
    for (int i = threadIdx.x; i < NPTS; i += 256) {
        float m0 = fmaxf(fmaxf(c0[i], c0[NPTS + i]),
                         fmaxf(c0[2 * NPTS + i], c0[3 * NPTS + i]));
        float x = q0[3 * i], y = q0[3 * i + 1], z = q0[3 * i + 2];
        s += fmaf(m0, -2.0f, x * x + y * y + z * z);
        float m1 = fmaxf(fmaxf(c1[i], c1[NPTS + i]),
                         fmaxf(c1[2 * NPTS + i], c1[3 * NPTS + i]));
        x = q1[3 * i]; y = q1[3 * i + 1]; z = q1[3 * i + 2];
        s += fmaf(m1, -2.0f, x * x + y * y + z * z);
    }
    red[threadIdx.x] = s;
    __syncthreads();
    #pragma unroll
    for (int off = 128; off > 0; off >>= 1) {
        if (threadIdx.x < off) red[threadIdx.x] += red[threadIdx.x + off];
        __syncthreads();
    }
    if (threadIdx.x == 0) out[b] = red[0] * (1.0f / NPTS);
}

extern "C" void kernel_launch(void* const* d_in, const int* in_sizes, int n_in,
                              void* d_out, int out_size, void* d_ws, size_t ws_size,
                              hipStream_t stream) {
    const float* tpl = (const float*)d_in[0];
    const float* src = (const float*)d_in[1];
    float* out = (float*)d_out;
    float* cm = (float*)d_ws;                                  // 1 MB

    chamfer_sweep<<<dim3(QBLKS, CH, 2 * B), BLOCK, 0, stream>>>(tpl, src, cm);
    chamfer_final<<<B, 256, 0, stream>>>(tpl, src, cm, out);
}

// Round 10
// 40.669 us; speedup vs baseline: 20.1535x; 20.1535x over previous
//
#include <hip/hip_runtime.h>
#include <stdint.h>

// Chamfer distance, B=4, N=M=8192, fp32 [B][N][3], out[B] = d01+d10.
//
// R10: revert to the PROVEN R7 3-kernel structure (R8/R9's fused prep
// triggers a scratch-spill storm: 2.9GB traffic, 810us — twice).
// Cost model: sweep = F (~11.8us per-block prologue) + V (~14.7us loop).
// This round kills most of F: the fa build's 6 scattered cold q-loads per
// thread are replaced by a coalesced float4 LDS stage of the block's 256
// queries (3KB at smem+32KB), then conflict-free LDS reads (3*r32 mod 32
// distinct). Tail: plain-store final (4 blocks, both dirs, no atomics).
// launch_bounds(256,4) = R6's counter-verified non-spilling config.
// Numerics identical to the verified R2..R7 path.

typedef __bf16 bf16x8 __attribute__((ext_vector_type(8)));
typedef float  f32x16 __attribute__((ext_vector_type(16)));
typedef float  f32x4  __attribute__((ext_vector_type(4)));

constexpr int B     = 4;
constexpr int NPTS  = 8192;
constexpr int BLOCK = 256;
constexpr int QPB   = 256;             // 4 waves * 64 queries
constexpr int QBLKS = NPTS / QPB;      // 32
constexpr int CH    = 4;               // point chunks per (b,dir)
constexpr int CPTS  = NPTS / CH;       // 2048 points per chunk
constexpr int SPTS  = 512;             // points per LDS pass (16 KB/buffer)
constexpr int NPASS = CPTS / SPTS;     // 4
constexpr int TPP   = SPTS / 32;       // 16 tiles per pass
constexpr int GRPS  = NPTS / 32;       // 256 point-groups per cloud
constexpr int PASSBYTES = SPTS * 32;   // 16384 B
constexpr int RSTRIDE = 36;            // padded f32 per reduce row
constexpr int SMEMB = BLOCK * RSTRIDE * 4;            // 36864 B (>2x16KB+3KB)
constexpr size_t CMBYTES = (size_t)2 * B * CH * NPTS * sizeof(float); // 1 MB

__device__ inline void gload_lds16(const void* g, void* l) {
    __builtin_amdgcn_global_load_lds(
        (const __attribute__((address_space(1))) uint32_t*)g,
        (__attribute__((address_space(3))) uint32_t*)l, 16, 0, 0);
}

// ---- Kernel 1: prep point fragments (g-major per 32-pt group) -------------
// group base (1024 B): frags g0 of pts 0..31, then frags g1 of pts 0..31.
// g0(k0-7) = [pxh,pyh,pzh, pxl,pyl,pzl, pxh,pyh]
// g1(k8-15)= [pzh, nh, nl, pxl,pyl,pzl, 0, 0]
__global__ __launch_bounds__(BLOCK) void chamfer_prep(
    const float* __restrict__ tpl, const float* __restrict__ src,
    bf16x8* __restrict__ efrag)
{
    const int pt  = blockIdx.x * BLOCK + threadIdx.x;
    const int c   = blockIdx.y;              // dir*B + b
    const int b   = c & (B - 1);
    const int dir = c >> 2;
    const float* db = (dir == 0 ? src : tpl) + (size_t)b * NPTS * 3;

    float x = db[3 * pt], y = db[3 * pt + 1], z = db[3 * pt + 2];
    float n = -0.5f * (x * x + y * y + z * z);
    __bf16 hx = (__bf16)x, hy = (__bf16)y, hz = (__bf16)z;
    __bf16 lx = (__bf16)(x - (float)hx);
    __bf16 ly = (__bf16)(y - (float)hy);
    __bf16 lz = (__bf16)(z - (float)hz);
    __bf16 nh = (__bf16)n;
    __bf16 nl = (__bf16)(n - (float)nh);
    const __bf16 zb = (__bf16)0.0f;

    const int gi = pt >> 5, sl = pt & 31;
    size_t gb = ((size_t)c * GRPS + gi) * 64;
    efrag[gb + sl]      = (bf16x8){hx, hy, hz, lx, ly, lz, hx, hy};
    efrag[gb + 32 + sl] = (bf16x8){hz, nh, nl, lx, ly, lz, zb, zb};
}

// ---- Kernel 2: MFMA sweep -------------------------------------------------
__global__ __launch_bounds__(BLOCK, 4) void chamfer_sweep(
    const float* __restrict__ tpl, const float* __restrict__ src,
    const bf16x8* __restrict__ efrag,
    float* __restrict__ cm)                  // [2*B][CH][NPTS] chunk maxima
{
    __shared__ char smem[SMEMB];             // [0,32K): dbuf; [32K,+3K): qstage
                                             // whole range reused by reduce
    const int tid = threadIdx.x;
    const int l   = tid & 63;
    const int w   = tid >> 6;
    const int h   = l >> 5;                  // k-group (0: k0-7, 1: k8-15)
    const int r32 = l & 31;                  // A row / B col within tile
    const int c   = blockIdx.z;              // dir*B + b
    const int b   = c & (B - 1);
    const int dir = c >> 2;
    const float* q = (dir == 0 ? tpl : src) + (size_t)b * NPTS * 3;
    const char* eb = (const char*)efrag
                   + ((size_t)c * GRPS + blockIdx.y * (CPTS / 32)) * 1024;

    // Prologue: issue pass-0 staging first (latency hides under q stage).
    #pragma unroll
    for (int i = 0; i < 4; ++i) {
        int off = (w * 4 + i) * 1024;
        gload_lds16(eb + off + l * 16, smem + off);
    }

    // Coalesced q stage: this block's 256 queries (3072 B) -> LDS scratch.
    float* qs = (float*)(smem + 32768);
    {
        const float4* qg4 = (const float4*)(q + (size_t)blockIdx.x * QPB * 3);
        if (tid < 192) ((float4*)qs)[tid] = qg4[tid];
    }
    __syncthreads();                         // qstage + pass-0 loads landed

    // A fragments: row = r32, k = h*8 + e. 64 queries per wave.
    // g0 = [qxh,qyh,qzh, qxh,qyh,qzh, qxl,qyl]; g1 = [qzl,1,1, qxl,qyl,qzl,0,0]
    const __bf16 one = (__bf16)1.0f, zb = (__bf16)0.0f;
    bf16x8 fa[2];
    #pragma unroll
    for (int f = 0; f < 2; ++f) {
        int qloc = w * 64 + f * 32 + r32;    // 3*r32 mod 32 distinct: no conflicts
        float x = qs[3 * qloc], y = qs[3 * qloc + 1], z = qs[3 * qloc + 2];
        __bf16 hx = (__bf16)x, hy = (__bf16)y, hz = (__bf16)z;
        __bf16 lx = (__bf16)(x - (float)hx);
        __bf16 ly = (__bf16)(y - (float)hy);
        __bf16 lz = (__bf16)(z - (float)hz);
        if (h == 0) fa[f] = (bf16x8){hx, hy, hz, hx, hy, hz, lx, ly};
        else        fa[f] = (bf16x8){lz, one, one, lx, ly, lz, zb, zb};
    }

    f32x16 best0, best1, zc;
    #pragma unroll
    for (int r = 0; r < 16; ++r) { best0[r] = -3.4e38f; best1[r] = -3.4e38f; zc[r] = 0.0f; }

    const int idx0 = h * 32 + r32;           // contiguous 16B/lane per half-wave
    for (int gp = 0; gp < NPASS; ++gp) {
        __syncthreads();                     // pass-gp buffer ready; other free
        if (gp + 1 < NPASS) {
            const char* ebn = eb + (gp + 1) * PASSBYTES;
            char* dst = smem + ((gp + 1) & 1) * 16384;
            #pragma unroll
            for (int i = 0; i < 4; ++i) {
                int off = (w * 4 + i) * 1024;
                gload_lds16(ebn + off + l * 16, dst + off);
            }
        }
        const bf16x8* sb = (const bf16x8*)(smem + (gp & 1) * 16384);
        __builtin_amdgcn_s_setprio(1);
        #pragma unroll
        for (int t = 0; t < TPP; t += 2) {
            bf16x8 bv0 = sb[t * 64 + idx0];
            bf16x8 bv1 = sb[(t + 1) * 64 + idx0];
            f32x16 d0 = __builtin_amdgcn_mfma_f32_32x32x16_bf16(fa[0], bv0, zc, 0, 0, 0);
            f32x16 d1 = __builtin_amdgcn_mfma_f32_32x32x16_bf16(fa[0], bv1, zc, 0, 0, 0);
            f32x16 e0 = __builtin_amdgcn_mfma_f32_32x32x16_bf16(fa[1], bv0, zc, 0, 0, 0);
            f32x16 e1 = __builtin_amdgcn_mfma_f32_32x32x16_bf16(fa[1], bv1, zc, 0, 0, 0);
            #pragma unroll
            for (int r = 0; r < 16; ++r)
                best0[r] = fmaxf(fmaxf(best0[r], d0[r]), d1[r]);   // -> v_max3
            #pragma unroll
            for (int r = 0; r < 16; ++r)
                best1[r] = fmaxf(fmaxf(best1[r], e0[r]), e1[r]);
        }
        __builtin_amdgcn_s_setprio(0);
    }

    // Epilogue: LDS transpose reduce (no wave shuffles, no atomics).
    // D layout: col = r32, row = (r&3) + 8*(r>>2) + 4*h.
    __syncthreads();                         // all waves done reading sbuf
    float* red = (float*)smem;
    #pragma unroll
    for (int r = 0; r < 16; ++r) {
        int row = (r & 3) + 8 * (r >> 2) + 4 * h;
        red[(w * 64 + row) * RSTRIDE + r32]      = best0[r];
        red[(w * 64 + 32 + row) * RSTRIDE + r32] = best1[r];
    }
    __syncthreads();
    const float* rr = red + tid * RSTRIDE;
    float m = -3.4e38f;
    #pragma unroll
    for (int j = 0; j < 8; ++j) {
        f32x4 v = *(const f32x4*)(rr + 4 * j);
        m = fmaxf(m, fmaxf(fmaxf(v.x, v.y), fmaxf(v.z, v.w)));
    }
    cm[((size_t)c * CH + blockIdx.y) * NPTS + blockIdx.x * QPB + tid] = m;
}

// ---- Kernel 3: out[b] = mean_q dist0 + mean_q dist1 (plain store) ---------
__global__ __launch_bounds__(256) void chamfer_final(
    const float* __restrict__ tpl, const float* __restrict__ src,
    const float* __restrict__ cm, float* __restrict__ out)
{
    __shared__ float red[256];
    const int b = blockIdx.x;
    const float* q0 = tpl + (size_t)b * NPTS * 3;      // dir0 queries
    const float* q1 = src + (size_t)b * NPTS * 3;      // dir1 queries
    const float* c0 = cm + (size_t)b * CH * NPTS;
    const float* c1 = cm + (size_t)(B + b) * CH * NPTS;

    float s = 0.f;
    for (int i = threadIdx.x; i < NPTS; i += 256) {
        float m0 = fmaxf(fmaxf(c0[i], c0[NPTS + i]),
                         fmaxf(c0[2 * NPTS + i], c0[3 * NPTS + i]));
        float x = q0[3 * i], y = q0[3 * i + 1], z = q0[3 * i + 2];
        s += fmaf(m0, -2.0f, x * x + y * y + z * z);
        float m1 = fmaxf(fmaxf(c1[i], c1[NPTS + i]),
                         fmaxf(c1[2 * NPTS + i], c1[3 * NPTS + i]));
        x = q1[3 * i]; y = q1[3 * i + 1]; z = q1[3 * i + 2];
        s += fmaf(m1, -2.0f, x * x + y * y + z * z);
    }
    red[threadIdx.x] = s;
    __syncthreads();
    #pragma unroll
    for (int off = 128; off > 0; off >>= 1) {
        if (threadIdx.x < off) red[threadIdx.x] += red[threadIdx.x + off];
        __syncthreads();
    }
    if (threadIdx.x == 0) out[b] = red[0] * (1.0f / NPTS);
}

extern "C" void kernel_launch(void* const* d_in, const int* in_sizes, int n_in,
                              void* d_out, int out_size, void* d_ws, size_t ws_size,
                              hipStream_t stream) {
    const float* tpl = (const float*)d_in[0];
    const float* src = (const float*)d_in[1];
    float* out = (float*)d_out;
    float* cm      = (float*)d_ws;                             // 1 MB
    bf16x8* efrag  = (bf16x8*)((char*)d_ws + CMBYTES);         // 2 MB

    chamfer_prep <<<dim3(NPTS / BLOCK, 2 * B), BLOCK, 0, stream>>>(tpl, src, efrag);
    chamfer_sweep<<<dim3(QBLKS, CH, 2 * B),    BLOCK, 0, stream>>>(tpl, src, efrag, cm);
    chamfer_final<<<B, 256, 0, stream>>>(tpl, src, cm, out);
}